// Round 10
// baseline (992.813 us; speedup 1.0000x reference)
//
#include <hip/hip_runtime.h>
#include <hip/hip_fp16.h>
#include <math.h>

#define NB 32
#define NN 512
#define DD 256
#define NROW  (NB*NN)      // 16384 rows per input
#define NELEM (NB*NN*DD)   // 4194304 elements per input

constexpr float INV_EPS   = 10.0f;
constexpr float F_TINY    = 1e-16f;
constexpr float F_NORMEPS = 1e-8f;
constexpr float MARG      = 1.0f / 512.0f;   // a = b = 1/n

// bars: one 256B line per batch = 64 ints; flags[b*64 + o*8 + w] = last
// iteration for which stripe o / wave w of batch b has published its cp
// partial (monotonic, store-only release; readers acquire).
#define BARS_N 2048

typedef __attribute__((ext_vector_type(8))) short bf16x8;
typedef __attribute__((ext_vector_type(4))) float f32x4;

__device__ __forceinline__ unsigned short f2bf(float f) {
    unsigned u = __float_as_uint(f);
    u += 0x7fffu + ((u >> 16) & 1u);          // round-to-nearest-even
    return (unsigned short)(u >> 16);
}

// ---------------------------------------------------------------------------
// Fused: row norms of x,y + bf16 convert + zero cost + zero barrier flags.
// One wave per row (256 floats, float4/lane). 8192 blocks x 256.
// (Verbatim from the passing R5/R8 build.)
// ---------------------------------------------------------------------------
__global__ __launch_bounds__(256) void norms_convert(
        const float* __restrict__ x, const float* __restrict__ y,
        float* __restrict__ nx, float* __restrict__ ny,
        unsigned short* __restrict__ xh, unsigned short* __restrict__ yh,
        float* __restrict__ cost, int* __restrict__ bars) {
    if (blockIdx.x == 0) {
        if (threadIdx.x < NB) cost[threadIdx.x] = 0.0f;
        for (int i = threadIdx.x; i < BARS_N; i += 256) bars[i] = 0;
    }
    int w = threadIdx.x >> 6, l = threadIdx.x & 63;
    int row = blockIdx.x * 4 + w;             // 0..32767
    bool isx = row < NROW;
    int r = isx ? row : row - NROW;
    const float* src = (isx ? x : y) + (size_t)r * DD;
    float4 v = ((const float4*)src)[l];
    float ss = v.x * v.x + v.y * v.y + v.z * v.z + v.w * v.w;
#pragma unroll
    for (int off = 32; off; off >>= 1) ss += __shfl_xor(ss, off);

    unsigned short* ph = (isx ? xh : yh) + (size_t)r * DD + l * 4;
    *(ushort4*)ph = make_ushort4(f2bf(v.x), f2bf(v.y), f2bf(v.z), f2bf(v.w));
    if (l == 0) (isx ? nx : ny)[r] = sqrtf(ss);
}

// ---------------------------------------------------------------------------
// C[b,n,m] = 1 - <x_n,y_m>/max(|x_n||y_m|, 1e-8), single bf16 MFMA.
// Fused epilogue also writes E = fp16(exp(-C/eps)).
// 128x128 tile, BK=32, 256 thr. XOR-swizzled LDS.
// (Verbatim from the passing R5/R8 build.)
// ---------------------------------------------------------------------------
__global__ __launch_bounds__(256) void gemm_cos_mfma(
        const unsigned short* __restrict__ xh, const unsigned short* __restrict__ yh,
        const float* __restrict__ nx, const float* __restrict__ ny,
        float* __restrict__ C, __half* __restrict__ Ef) {
    int blk = blockIdx.x;
    int b = blk >> 4, ti = (blk >> 2) & 3, tj = blk & 3;
    __shared__ short Ah[128][32], Bh[128][32];
    const unsigned short* xbh = xh + ((size_t)b * NN + ti * 128) * DD;
    const unsigned short* ybh = yh + ((size_t)b * NN + tj * 128) * DD;
    int t = threadIdx.x, w = t >> 6, l = t & 63;
    int rw = w * 32, q = l >> 4, low = l & 15;

    f32x4 acc[2][8];
#pragma unroll
    for (int i = 0; i < 2; ++i)
#pragma unroll
        for (int j = 0; j < 8; ++j) acc[i][j] = (f32x4){0.f, 0.f, 0.f, 0.f};

    int sr = t >> 1, h = t & 1;               // staging: 2 threads/row
    int c0i = 2 * h, c1i = 2 * h + 1;         // logical 16B chunks
    int sw0 = (c0i ^ ((sr >> 1) & 3)) * 8;    // swizzled short offsets
    int sw1 = (c1i ^ ((sr >> 1) & 3)) * 8;

    for (int k0 = 0; k0 < DD; k0 += 32) {
        {
            const int4* ga = (const int4*)(xbh + (size_t)sr * DD + k0);
            const int4* gc = (const int4*)(ybh + (size_t)sr * DD + k0);
            int4 a0 = ga[c0i], a1 = ga[c1i];
            int4 c0 = gc[c0i], c1 = gc[c1i];
            *(int4*)&Ah[sr][sw0] = a0; *(int4*)&Ah[sr][sw1] = a1;
            *(int4*)&Bh[sr][sw0] = c0; *(int4*)&Bh[sr][sw1] = c1;
        }
        __syncthreads();

        bf16x8 ah[2];
#pragma unroll
        for (int ti2 = 0; ti2 < 2; ++ti2) {
            int m = rw + ti2 * 16 + low;
            int pq = (q ^ ((m >> 1) & 3)) * 8;
            ah[ti2] = *(const bf16x8*)&Ah[m][pq];
        }
#pragma unroll
        for (int tj2 = 0; tj2 < 8; ++tj2) {
            int n = tj2 * 16 + low;
            int pq = (q ^ ((n >> 1) & 3)) * 8;
            bf16x8 bh = *(const bf16x8*)&Bh[n][pq];
#pragma unroll
            for (int ti2 = 0; ti2 < 2; ++ti2)
                acc[ti2][tj2] = __builtin_amdgcn_mfma_f32_16x16x32_bf16(
                    ah[ti2], bh, acc[ti2][tj2], 0, 0, 0);
        }
        __syncthreads();
    }

    // epilogue: C/D layout col=lane&15, row=(lane>>4)*4+reg  [m89-corrected]
    float*  Cb = C  + (size_t)b * NN * NN;
    __half* Eb = Ef + (size_t)b * NN * NN;
#pragma unroll
    for (int ti2 = 0; ti2 < 2; ++ti2) {
#pragma unroll
        for (int tj2 = 0; tj2 < 8; ++tj2) {
            int gm0 = ti * 128 + rw + ti2 * 16 + q * 4;
            int gn  = tj * 128 + tj2 * 16 + low;
            float nyc = ny[b * NN + gn];
            f32x4 a = acc[ti2][tj2];
#pragma unroll
            for (int reg = 0; reg < 4; ++reg) {
                int gm = gm0 + reg;
                float d = 1.0f - a[reg] / fmaxf(nx[b * NN + gm] * nyc, F_NORMEPS);
                Cb[(size_t)gm * NN + gn] = d;
                Eb[(size_t)gm * NN + gn] = __float2half(__expf(-INV_EPS * d));
            }
        }
    }
}

// ---------------------------------------------------------------------------
// Fully fused Sinkhorn, R10 = R8 geometry (256 blocks, 64-row stripes,
// 1 block/CU, E in registers) with the 2-sync iteration protocol:
//  - per-(stripe,wave) flags: wave w of stripe o RELEASE-stores flags[o*8+w]
//    right after its cpw stores (vmcnt is per-wave -> release drains exactly
//    that wave's cp stores). Deletes the arrive-side block sync.
//  - all-lane ACQUIRE poll: every wave polls all 64 flags via one coalesced
//    lane-load + __all. Acquire pairs with the release store (cp handoff is
//    memory-model-clean) and orders the subsequent cp loads. Deletes the
//    wait-side block sync.
//  - hazards: sW reads precede sync(c), sW writes for t+1 follow it; sWP
//    writes for t+1 follow sync(b)-t+1, cs-sum reads precede it; cp buffer
//    reuse gated by all-flags>=t, each flag t stored after that wave's
//    cp(t-1) read. Same invariants as R5/R8, wave-granular.
// ---------------------------------------------------------------------------
__global__ __launch_bounds__(512, 2) void sink_fused(
        const __half* __restrict__ Ef, const float* __restrict__ C,
        float* __restrict__ cp0, float* __restrict__ cp1,
        float* __restrict__ pi, float* __restrict__ cost,
        int* __restrict__ bars) {
    int blk = blockIdx.x;
    int xcd = blk & 7, qq = blk >> 3;
    int o = qq & 7;                       // stripe slot within batch
    int b = ((qq >> 3) << 3) | xcd;       // batch (8 stripes share blk%8/XCD)
    int tt = threadIdx.x, w = tt >> 6, l = tt & 63;
    int* flags = &bars[b * 64];           // 64 per-(stripe,wave) flags, 1 line

    __shared__ float sW[NN];              // w_m (later reused for Q)
    __shared__ float sWP[8][NN];          // per-wave column partials
    __shared__ float sPart[8];

    // ---- E tile: global -> registers, resident across all 15 iterations
    int4 raw[8];
    {
        const __half* Eb = Ef + ((size_t)b * NN + o * 64 + w * 8) * NN + 8 * l;
#pragma unroll
        for (int i = 0; i < 8; ++i)
            raw[i] = *(const int4*)(Eb + (size_t)i * NN);
    }

    float A[8], Pr[8];
#pragma unroll
    for (int i = 0; i < 8; ++i) { A[i] = 1.0f; Pr[i] = 0.0f; }
    float Br = 1.0f;                      // cumulative col scaling

    float* cpr = cp0;                     // read buffer
    float* cpw = cp1;                     // iter 1 writes cp1

    for (int t = 1; t <= 15; ++t) {
        // ---- step 1: finish v_{t-1}; t==1 has v_0=1, B_0=1
        if (t == 1) {
            sW[tt] = 1.0f;
        } else {
            // all-lane acquire poll: lane l watches flag l of this batch
            while (!__all(__hip_atomic_load(&flags[l], __ATOMIC_ACQUIRE,
                                            __HIP_MEMORY_SCOPE_AGENT) >= t - 1))
                __builtin_amdgcn_s_sleep(1);
            float sv = 0.0f;
#pragma unroll
            for (int k = 0; k < 8; ++k)
                sv += __hip_atomic_load(
                    &cpr[(size_t)(b * 8 + k) * NN + tt],
                    __ATOMIC_RELAXED, __HIP_MEMORY_SCOPE_AGENT);
            float vv = MARG / (Br * sv + F_TINY);
            Br *= vv;                      // B_{t-1}
            sW[tt] = Br * vv;              // w_m
        }
        __syncthreads();                  // (b) sW ready

        float wr[8];
        *(float4*)&wr[0] = *(const float4*)&sW[8 * l];
        *(float4*)&wr[4] = *(const float4*)&sW[8 * l + 4];

        // ---- step 2: u for own 8 rows (E from registers)
#pragma unroll
        for (int i = 0; i < 8; ++i) {
            const __half* hv = (const __half*)&raw[i];
            float s = 0.0f;
#pragma unroll
            for (int e = 0; e < 8; ++e) s = fmaf(__half2float(hv[e]), wr[e], s);
#pragma unroll
            for (int off = 32; off; off >>= 1) s += __shfl_xor(s, off);
            float uu = MARG / (A[i] * s + F_TINY);
            A[i] *= uu;
            if (t == 15) Pr[i] = A[i] * uu;   // P = A_15 * u_15 (all lanes)
        }

        // ---- step 3: column partials over own stripe with A_t
        float p[8];
#pragma unroll
        for (int e = 0; e < 8; ++e) p[e] = 0.0f;
#pragma unroll
        for (int i = 0; i < 8; ++i) {
            const __half* hv = (const __half*)&raw[i];
#pragma unroll
            for (int e = 0; e < 8; ++e)
                p[e] = fmaf(__half2float(hv[e]), A[i], p[e]);
        }
        *(float4*)&sWP[w][8 * l]     = make_float4(p[0], p[1], p[2], p[3]);
        *(float4*)&sWP[w][8 * l + 4] = make_float4(p[4], p[5], p[6], p[7]);
        __syncthreads();                  // (c) sWP ready
        float cs = 0.0f;
#pragma unroll
        for (int ww = 0; ww < 8; ++ww) cs += sWP[ww][tt];
        cpw[(size_t)(b * 8 + o) * NN + tt] = cs;

        // ---- per-wave arrive: RELEASE drains this wave's cpw stores
        //      (vmcnt is per-wave), then publish its flag. No block sync.
        if (l == 0)
            __hip_atomic_store(&flags[o * 8 + w], t, __ATOMIC_RELEASE,
                               __HIP_MEMORY_SCOPE_AGENT);

        float* tmp = cpr; cpr = cpw; cpw = tmp;   // swap buffers
    }

    // ---- finish Q: wait for all iter-15 flags, then full Q per block
    while (!__all(__hip_atomic_load(&flags[l], __ATOMIC_ACQUIRE,
                                    __HIP_MEMORY_SCOPE_AGENT) >= 15))
        __builtin_amdgcn_s_sleep(1);
    {
        float sv = 0.0f;
#pragma unroll
        for (int k = 0; k < 8; ++k)
            sv += __hip_atomic_load(
                &cpr[(size_t)(b * 8 + k) * NN + tt],   // cp_15
                __ATOMIC_RELAXED, __HIP_MEMORY_SCOPE_AGENT);
        float vv = MARG / (Br * sv + F_TINY);           // Br = B_14
        sW[tt] = Br * vv * vv;            // Q_m = B_15 * v_15 (reuse sW)
    }
    __syncthreads();                      // Q visible block-wide

    // ---- pi phase: identical math to verified pi_cost (f32 C, __expf)
    float q0[8];
    *(float4*)&q0[0] = *(const float4*)&sW[4 * l];
    *(float4*)&q0[4] = *(const float4*)&sW[256 + 4 * l];
    const float* Cb = C + (size_t)b * NN * NN;
    float* pib = pi + (size_t)b * NN * NN;
    float csum = 0.0f;
#pragma unroll 1
    for (int i = 0; i < 8; ++i) {
        int r = o * 64 + w * 8 + i;
        float pf = Pr[i];
        const float* crow = Cb + (size_t)r * NN;
        float* prow = pib + (size_t)r * NN;
        float4 c0 = *(const float4*)(crow + 4 * l);
        float4 c1 = *(const float4*)(crow + 256 + 4 * l);
        float pv0 = pf * q0[0] * __expf(-INV_EPS * c0.x);
        float pv1 = pf * q0[1] * __expf(-INV_EPS * c0.y);
        float pv2 = pf * q0[2] * __expf(-INV_EPS * c0.z);
        float pv3 = pf * q0[3] * __expf(-INV_EPS * c0.w);
        float pv4 = pf * q0[4] * __expf(-INV_EPS * c1.x);
        float pv5 = pf * q0[5] * __expf(-INV_EPS * c1.y);
        float pv6 = pf * q0[6] * __expf(-INV_EPS * c1.z);
        float pv7 = pf * q0[7] * __expf(-INV_EPS * c1.w);
        *(float4*)(prow + 4 * l)       = make_float4(pv0, pv1, pv2, pv3);
        *(float4*)(prow + 256 + 4 * l) = make_float4(pv4, pv5, pv6, pv7);
        csum = fmaf(pv0, c0.x, csum); csum = fmaf(pv1, c0.y, csum);
        csum = fmaf(pv2, c0.z, csum); csum = fmaf(pv3, c0.w, csum);
        csum = fmaf(pv4, c1.x, csum); csum = fmaf(pv5, c1.y, csum);
        csum = fmaf(pv6, c1.z, csum); csum = fmaf(pv7, c1.w, csum);
    }
#pragma unroll
    for (int off = 32; off; off >>= 1) csum += __shfl_xor(csum, off);
    if (l == 0) sPart[w] = csum;
    __syncthreads();
    if (tt == 0) {
        float tot = 0.0f;
#pragma unroll
        for (int ww = 0; ww < 8; ++ww) tot += sPart[ww];
        atomicAdd(&cost[b], tot);
    }
}

// ---------------------------------------------------------------------------
extern "C" void kernel_launch(void* const* d_in, const int* in_sizes, int n_in,
                              void* d_out, int out_size, void* d_ws, size_t ws_size,
                              hipStream_t stream) {
    const float* x = (const float*)d_in[0];
    const float* y = (const float*)d_in[1];
    float* out  = (float*)d_out;
    float* cost = out;                                   // [32]
    float* pi   = out + 32;                              // [32*512*512]
    float* C    = out + 32 + (size_t)NB * NN * NN;       // [32*512*512]

    // Workspace layout (verbatim R5/R8): all scratch in d_ws; pi written
    // exactly once at the end of sink_fused -> no aliasing, no grid barrier.
    float* ws = (float*)d_ws;
    float* nx = ws;                                   // 16384 f
    float* ny = ws + 16384;                           // 16384 f
    int*  bars = (int*)(ws + 32768);                  // 2048 ints (flags)
    unsigned short* xh = (unsigned short*)(ws + 65536);       // 8.39 MB
    unsigned short* yh = xh + NELEM;                          // 8.39 MB
    __half* Ef = (__half*)(yh + NELEM);                       // 16.78 MB
    float* cp0 = (float*)(Ef + (size_t)NB * NN * NN);         // 0.52 MB
    float* cp1 = cp0 + (size_t)NB * 8 * NN;                   // 0.52 MB

    norms_convert<<<dim3(8192), dim3(256), 0, stream>>>(
        x, y, nx, ny, xh, yh, cost, bars);
    gemm_cos_mfma<<<dim3(512), dim3(256), 0, stream>>>(
        xh, yh, nx, ny, C, Ef);

    const __half* Ef_p = Ef; const float* C_p = C;
    float* cp0_p = cp0; float* cp1_p = cp1;
    float* pi_p = pi; float* cost_p = cost; int* bars_p = bars;
    void* args[] = { &Ef_p, &C_p, &cp0_p, &cp1_p, &pi_p, &cost_p, &bars_p };
    hipLaunchCooperativeKernel(reinterpret_cast<void*>(sink_fused),
                               dim3(256), dim3(512), args, 0, stream);
}

// Round 11
// 185.067 us; speedup vs baseline: 5.3646x; 5.3646x over previous
//
#include <hip/hip_runtime.h>
#include <hip/hip_fp16.h>
#include <math.h>

#define NB 32
#define NN 512
#define DD 256
#define NROW  (NB*NN)      // 16384 rows per input
#define NELEM (NB*NN*DD)   // 4194304 elements per input

constexpr float INV_EPS   = 10.0f;
constexpr float F_TINY    = 1e-16f;
constexpr float F_NORMEPS = 1e-8f;
constexpr float MARG      = 1.0f / 512.0f;   // a = b = 1/n

// bars: one 256B line per batch; ints [b*64 + o] (o=0..7) hold the last
// completed iteration of stripe o of batch b (monotonic flags, no RMW).
#define BARS_N 2048

typedef __attribute__((ext_vector_type(8))) short bf16x8;
typedef __attribute__((ext_vector_type(4))) float f32x4;

__device__ __forceinline__ unsigned short f2bf(float f) {
    unsigned u = __float_as_uint(f);
    u += 0x7fffu + ((u >> 16) & 1u);          // round-to-nearest-even
    return (unsigned short)(u >> 16);
}

// ---------------------------------------------------------------------------
// Fused: row norms of x,y + bf16 convert + zero cost + zero barrier flags.
// One wave per row (256 floats, float4/lane). 8192 blocks x 256.
// (Verbatim from the passing R5/R8 build.)
// ---------------------------------------------------------------------------
__global__ __launch_bounds__(256) void norms_convert(
        const float* __restrict__ x, const float* __restrict__ y,
        float* __restrict__ nx, float* __restrict__ ny,
        unsigned short* __restrict__ xh, unsigned short* __restrict__ yh,
        float* __restrict__ cost, int* __restrict__ bars) {
    if (blockIdx.x == 0) {
        if (threadIdx.x < NB) cost[threadIdx.x] = 0.0f;
        for (int i = threadIdx.x; i < BARS_N; i += 256) bars[i] = 0;
    }
    int w = threadIdx.x >> 6, l = threadIdx.x & 63;
    int row = blockIdx.x * 4 + w;             // 0..32767
    bool isx = row < NROW;
    int r = isx ? row : row - NROW;
    const float* src = (isx ? x : y) + (size_t)r * DD;
    float4 v = ((const float4*)src)[l];
    float ss = v.x * v.x + v.y * v.y + v.z * v.z + v.w * v.w;
#pragma unroll
    for (int off = 32; off; off >>= 1) ss += __shfl_xor(ss, off);

    unsigned short* ph = (isx ? xh : yh) + (size_t)r * DD + l * 4;
    *(ushort4*)ph = make_ushort4(f2bf(v.x), f2bf(v.y), f2bf(v.z), f2bf(v.w));
    if (l == 0) (isx ? nx : ny)[r] = sqrtf(ss);
}

// ---------------------------------------------------------------------------
// C[b,n,m] = 1 - <x_n,y_m>/max(|x_n||y_m|, 1e-8), single bf16 MFMA.
// R11: writes ONLY C (f32). The old fp16 Ef store was 16.8M scattered 2-byte
// stores (~25% line efficiency); E is now recomputed in sink_fused from the
// SAME C f32 values -> bit-identical E, zero Ef traffic.
// 128x128 tile, BK=32, 256 thr. XOR-swizzled LDS.
// ---------------------------------------------------------------------------
__global__ __launch_bounds__(256) void gemm_cos_mfma(
        const unsigned short* __restrict__ xh, const unsigned short* __restrict__ yh,
        const float* __restrict__ nx, const float* __restrict__ ny,
        float* __restrict__ C) {
    int blk = blockIdx.x;
    int b = blk >> 4, ti = (blk >> 2) & 3, tj = blk & 3;
    __shared__ short Ah[128][32], Bh[128][32];
    const unsigned short* xbh = xh + ((size_t)b * NN + ti * 128) * DD;
    const unsigned short* ybh = yh + ((size_t)b * NN + tj * 128) * DD;
    int t = threadIdx.x, w = t >> 6, l = t & 63;
    int rw = w * 32, q = l >> 4, low = l & 15;

    f32x4 acc[2][8];
#pragma unroll
    for (int i = 0; i < 2; ++i)
#pragma unroll
        for (int j = 0; j < 8; ++j) acc[i][j] = (f32x4){0.f, 0.f, 0.f, 0.f};

    int sr = t >> 1, h = t & 1;               // staging: 2 threads/row
    int c0i = 2 * h, c1i = 2 * h + 1;         // logical 16B chunks
    int sw0 = (c0i ^ ((sr >> 1) & 3)) * 8;    // swizzled short offsets
    int sw1 = (c1i ^ ((sr >> 1) & 3)) * 8;

    for (int k0 = 0; k0 < DD; k0 += 32) {
        {
            const int4* ga = (const int4*)(xbh + (size_t)sr * DD + k0);
            const int4* gc = (const int4*)(ybh + (size_t)sr * DD + k0);
            int4 a0 = ga[c0i], a1 = ga[c1i];
            int4 c0 = gc[c0i], c1 = gc[c1i];
            *(int4*)&Ah[sr][sw0] = a0; *(int4*)&Ah[sr][sw1] = a1;
            *(int4*)&Bh[sr][sw0] = c0; *(int4*)&Bh[sr][sw1] = c1;
        }
        __syncthreads();

        bf16x8 ah[2];
#pragma unroll
        for (int ti2 = 0; ti2 < 2; ++ti2) {
            int m = rw + ti2 * 16 + low;
            int pq = (q ^ ((m >> 1) & 3)) * 8;
            ah[ti2] = *(const bf16x8*)&Ah[m][pq];
        }
#pragma unroll
        for (int tj2 = 0; tj2 < 8; ++tj2) {
            int n = tj2 * 16 + low;
            int pq = (q ^ ((n >> 1) & 3)) * 8;
            bf16x8 bh = *(const bf16x8*)&Bh[n][pq];
#pragma unroll
            for (int ti2 = 0; ti2 < 2; ++ti2)
                acc[ti2][tj2] = __builtin_amdgcn_mfma_f32_16x16x32_bf16(
                    ah[ti2], bh, acc[ti2][tj2], 0, 0, 0);
        }
        __syncthreads();
    }

    // epilogue: C/D layout col=lane&15, row=(lane>>4)*4+reg  [m89-corrected]
    float* Cb = C + (size_t)b * NN * NN;
#pragma unroll
    for (int ti2 = 0; ti2 < 2; ++ti2) {
#pragma unroll
        for (int tj2 = 0; tj2 < 8; ++tj2) {
            int gm0 = ti * 128 + rw + ti2 * 16 + q * 4;
            int gn  = tj * 128 + tj2 * 16 + low;
            float nyc = ny[b * NN + gn];
            f32x4 a = acc[ti2][tj2];
#pragma unroll
            for (int reg = 0; reg < 4; ++reg) {
                int gm = gm0 + reg;
                float d = 1.0f - a[reg] / fmaxf(nx[b * NN + gm] * nyc, F_NORMEPS);
                Cb[(size_t)gm * NN + gn] = d;
            }
        }
    }
}

// ---------------------------------------------------------------------------
// Fully fused Sinkhorn, R11 = R8 verbatim (256 blocks, 64-row stripes,
// E in registers, PROVEN 4-sync flag protocol) with one change: the E tile
// is computed at load from C f32 — raw[i] = fp16(__expf(-10*C)) — instead of
// reading a precomputed Ef. Same C values as the old gemm epilogue used ->
// bit-identical E, absmax unchanged. Ef buffer and its traffic deleted.
// ---------------------------------------------------------------------------
__global__ __launch_bounds__(512, 2) void sink_fused(
        const float* __restrict__ C,
        float* __restrict__ cp0, float* __restrict__ cp1,
        float* __restrict__ pi, float* __restrict__ cost,
        int* __restrict__ bars) {
    int blk = blockIdx.x;
    int xcd = blk & 7, qq = blk >> 3;
    int o = qq & 7;                       // stripe slot within batch
    int b = ((qq >> 3) << 3) | xcd;       // batch (8 stripes share blk%8/XCD)
    int tt = threadIdx.x, w = tt >> 6, l = tt & 63;
    int* flags = &bars[b * 64];           // 8 per-stripe flags, one line

    __shared__ float sW[NN];              // w_m (later reused for Q)
    __shared__ float sWP[8][NN];          // per-wave column partials
    __shared__ float sPart[8];

    // ---- E tile: compute fp16(exp(-10*C)) from f32 C, global -> registers,
    //      resident across all 15 iterations. Bit-identical to the old Ef.
    int4 raw[8];
    {
        const float* Cl = C + ((size_t)b * NN + o * 64 + w * 8) * NN + 8 * l;
#pragma unroll
        for (int i = 0; i < 8; ++i) {
            float4 c0 = *(const float4*)(Cl + (size_t)i * NN);
            float4 c1 = *(const float4*)(Cl + (size_t)i * NN + 4);
            __half h[8];
            h[0] = __float2half(__expf(-INV_EPS * c0.x));
            h[1] = __float2half(__expf(-INV_EPS * c0.y));
            h[2] = __float2half(__expf(-INV_EPS * c0.z));
            h[3] = __float2half(__expf(-INV_EPS * c0.w));
            h[4] = __float2half(__expf(-INV_EPS * c1.x));
            h[5] = __float2half(__expf(-INV_EPS * c1.y));
            h[6] = __float2half(__expf(-INV_EPS * c1.z));
            h[7] = __float2half(__expf(-INV_EPS * c1.w));
            raw[i] = *(const int4*)h;
        }
    }

    float A[8], Pr[8];
#pragma unroll
    for (int i = 0; i < 8; ++i) { A[i] = 1.0f; Pr[i] = 0.0f; }
    float Br = 1.0f;                      // cumulative col scaling

    float* cpr = cp0;                     // read buffer
    float* cpw = cp1;                     // iter 1 writes cp1

    for (int t = 1; t <= 15; ++t) {
        // ---- step 1: finish v_{t-1}; t==1 has v_0=1, B_0=1
        if (t == 1) {
            sW[tt] = 1.0f;
        } else {
            // wait: all 8 stripes have completed iteration t-1
            if (tt < 8) {
                while (__hip_atomic_load(&flags[tt], __ATOMIC_RELAXED,
                                         __HIP_MEMORY_SCOPE_AGENT) < t - 1)
                    __builtin_amdgcn_s_sleep(1);
            }
            __syncthreads();
            float sv = 0.0f;
#pragma unroll
            for (int k = 0; k < 8; ++k)
                sv += __hip_atomic_load(
                    &cpr[(size_t)(b * 8 + k) * NN + tt],
                    __ATOMIC_RELAXED, __HIP_MEMORY_SCOPE_AGENT);
            float vv = MARG / (Br * sv + F_TINY);
            Br *= vv;                      // B_{t-1}
            sW[tt] = Br * vv;              // w_m
        }
        __syncthreads();                  // sW ready

        float wr[8];
        *(float4*)&wr[0] = *(const float4*)&sW[8 * l];
        *(float4*)&wr[4] = *(const float4*)&sW[8 * l + 4];

        // ---- step 2: u for own 8 rows (E from registers)
#pragma unroll
        for (int i = 0; i < 8; ++i) {
            const __half* hv = (const __half*)&raw[i];
            float s = 0.0f;
#pragma unroll
            for (int e = 0; e < 8; ++e) s = fmaf(__half2float(hv[e]), wr[e], s);
#pragma unroll
            for (int off = 32; off; off >>= 1) s += __shfl_xor(s, off);
            float uu = MARG / (A[i] * s + F_TINY);
            A[i] *= uu;
            if (t == 15) Pr[i] = A[i] * uu;   // P = A_15 * u_15 (all lanes)
        }

        // ---- step 3: column partials over own stripe with A_t
        float p[8];
#pragma unroll
        for (int e = 0; e < 8; ++e) p[e] = 0.0f;
#pragma unroll
        for (int i = 0; i < 8; ++i) {
            const __half* hv = (const __half*)&raw[i];
#pragma unroll
            for (int e = 0; e < 8; ++e)
                p[e] = fmaf(__half2float(hv[e]), A[i], p[e]);
        }
        *(float4*)&sWP[w][8 * l]     = make_float4(p[0], p[1], p[2], p[3]);
        *(float4*)&sWP[w][8 * l + 4] = make_float4(p[4], p[5], p[6], p[7]);
        __syncthreads();
        float cs = 0.0f;
#pragma unroll
        for (int ww = 0; ww < 8; ++ww) cs += sWP[ww][tt];
        cpw[(size_t)(b * 8 + o) * NN + tt] = cs;

        // ---- arrive: syncthreads drains vmcnt (cp stores at L2, L1 is
        //      write-through), then one flag STORE (no RMW chain).
        __syncthreads();
        if (tt == 0)
            __hip_atomic_store(&flags[o], t, __ATOMIC_RELAXED,
                               __HIP_MEMORY_SCOPE_AGENT);

        float* tmp = cpr; cpr = cpw; cpw = tmp;   // swap buffers
    }

    // ---- finish Q: wait for iter-15 flags, then full Q vector per block
    if (tt < 8) {
        while (__hip_atomic_load(&flags[tt], __ATOMIC_RELAXED,
                                 __HIP_MEMORY_SCOPE_AGENT) < 15)
            __builtin_amdgcn_s_sleep(1);
    }
    __syncthreads();
    {
        float sv = 0.0f;
#pragma unroll
        for (int k = 0; k < 8; ++k)
            sv += __hip_atomic_load(
                &cpr[(size_t)(b * 8 + k) * NN + tt],   // cp_15
                __ATOMIC_RELAXED, __HIP_MEMORY_SCOPE_AGENT);
        float vv = MARG / (Br * sv + F_TINY);           // Br = B_14
        sW[tt] = Br * vv * vv;            // Q_m = B_15 * v_15 (reuse sW)
    }
    __syncthreads();                      // Q visible block-wide

    // ---- pi phase: identical math to verified pi_cost (f32 C, __expf)
    float q0[8];
    *(float4*)&q0[0] = *(const float4*)&sW[4 * l];
    *(float4*)&q0[4] = *(const float4*)&sW[256 + 4 * l];
    const float* Cb = C + (size_t)b * NN * NN;
    float* pib = pi + (size_t)b * NN * NN;
    float csum = 0.0f;
#pragma unroll 1
    for (int i = 0; i < 8; ++i) {
        int r = o * 64 + w * 8 + i;
        float pf = Pr[i];
        const float* crow = Cb + (size_t)r * NN;
        float* prow = pib + (size_t)r * NN;
        float4 c0 = *(const float4*)(crow + 4 * l);
        float4 c1 = *(const float4*)(crow + 256 + 4 * l);
        float pv0 = pf * q0[0] * __expf(-INV_EPS * c0.x);
        float pv1 = pf * q0[1] * __expf(-INV_EPS * c0.y);
        float pv2 = pf * q0[2] * __expf(-INV_EPS * c0.z);
        float pv3 = pf * q0[3] * __expf(-INV_EPS * c0.w);
        float pv4 = pf * q0[4] * __expf(-INV_EPS * c1.x);
        float pv5 = pf * q0[5] * __expf(-INV_EPS * c1.y);
        float pv6 = pf * q0[6] * __expf(-INV_EPS * c1.z);
        float pv7 = pf * q0[7] * __expf(-INV_EPS * c1.w);
        *(float4*)(prow + 4 * l)       = make_float4(pv0, pv1, pv2, pv3);
        *(float4*)(prow + 256 + 4 * l) = make_float4(pv4, pv5, pv6, pv7);
        csum = fmaf(pv0, c0.x, csum); csum = fmaf(pv1, c0.y, csum);
        csum = fmaf(pv2, c0.z, csum); csum = fmaf(pv3, c0.w, csum);
        csum = fmaf(pv4, c1.x, csum); csum = fmaf(pv5, c1.y, csum);
        csum = fmaf(pv6, c1.z, csum); csum = fmaf(pv7, c1.w, csum);
    }
#pragma unroll
    for (int off = 32; off; off >>= 1) csum += __shfl_xor(csum, off);
    if (l == 0) sPart[w] = csum;
    __syncthreads();
    if (tt == 0) {
        float tot = 0.0f;
#pragma unroll
        for (int ww = 0; ww < 8; ++ww) tot += sPart[ww];
        atomicAdd(&cost[b], tot);
    }
}

// ---------------------------------------------------------------------------
extern "C" void kernel_launch(void* const* d_in, const int* in_sizes, int n_in,
                              void* d_out, int out_size, void* d_ws, size_t ws_size,
                              hipStream_t stream) {
    const float* x = (const float*)d_in[0];
    const float* y = (const float*)d_in[1];
    float* out  = (float*)d_out;
    float* cost = out;                                   // [32]
    float* pi   = out + 32;                              // [32*512*512]
    float* C    = out + 32 + (size_t)NB * NN * NN;       // [32*512*512]

    // Workspace: nx/ny, flags, bf16 inputs, cp double buffer. Ef deleted.
    float* ws = (float*)d_ws;
    float* nx = ws;                                   // 16384 f
    float* ny = ws + 16384;                           // 16384 f
    int*  bars = (int*)(ws + 32768);                  // 2048 ints (flags)
    unsigned short* xh = (unsigned short*)(ws + 65536);       // 8.39 MB
    unsigned short* yh = xh + NELEM;                          // 8.39 MB
    float* cp0 = (float*)(yh + NELEM);                        // 0.52 MB
    float* cp1 = cp0 + (size_t)NB * 8 * NN;                   // 0.52 MB

    norms_convert<<<dim3(8192), dim3(256), 0, stream>>>(
        x, y, nx, ny, xh, yh, cost, bars);
    gemm_cos_mfma<<<dim3(512), dim3(256), 0, stream>>>(
        xh, yh, nx, ny, C);

    const float* C_p = C;
    float* cp0_p = cp0; float* cp1_p = cp1;
    float* pi_p = pi; float* cost_p = cost; int* bars_p = bars;
    void* args[] = { &C_p, &cp0_p, &cp1_p, &pi_p, &cost_p, &bars_p };
    hipLaunchCooperativeKernel(reinterpret_cast<void*>(sink_fused),
                               dim3(256), dim3(512), args, 0, stream);
}

// Round 12
// 184.368 us; speedup vs baseline: 5.3849x; 1.0038x over previous
//
#include <hip/hip_runtime.h>
#include <hip/hip_fp16.h>
#include <math.h>

#define NB 32
#define NN 512
#define DD 256
#define NROW  (NB*NN)      // 16384 rows per input
#define NELEM (NB*NN*DD)   // 4194304 elements per input

constexpr float INV_EPS   = 10.0f;
constexpr float F_TINY    = 1e-16f;
constexpr float F_NORMEPS = 1e-8f;
constexpr float MARG      = 1.0f / 512.0f;   // a = b = 1/n

// bars: one 256B line per batch; ints [b*64 + o] (o=0..7) hold the last
// completed iteration of stripe o of batch b (monotonic flags, no RMW).
#define BARS_N 2048

typedef __attribute__((ext_vector_type(8))) short bf16x8;
typedef __attribute__((ext_vector_type(4))) float f32x4;

__device__ __forceinline__ unsigned short f2bf(float f) {
    unsigned u = __float_as_uint(f);
    u += 0x7fffu + ((u >> 16) & 1u);          // round-to-nearest-even
    return (unsigned short)(u >> 16);
}

// ---------------------------------------------------------------------------
// Fused: row norms of x,y + bf16 convert + zero cost + zero barrier flags.
// One wave per row (256 floats, float4/lane). 8192 blocks x 256.
// (Verbatim from the passing R5/R8/R11 build.)
// ---------------------------------------------------------------------------
__global__ __launch_bounds__(256) void norms_convert(
        const float* __restrict__ x, const float* __restrict__ y,
        float* __restrict__ nx, float* __restrict__ ny,
        unsigned short* __restrict__ xh, unsigned short* __restrict__ yh,
        float* __restrict__ cost, int* __restrict__ bars) {
    if (blockIdx.x == 0) {
        if (threadIdx.x < NB) cost[threadIdx.x] = 0.0f;
        for (int i = threadIdx.x; i < BARS_N; i += 256) bars[i] = 0;
    }
    int w = threadIdx.x >> 6, l = threadIdx.x & 63;
    int row = blockIdx.x * 4 + w;             // 0..32767
    bool isx = row < NROW;
    int r = isx ? row : row - NROW;
    const float* src = (isx ? x : y) + (size_t)r * DD;
    float4 v = ((const float4*)src)[l];
    float ss = v.x * v.x + v.y * v.y + v.z * v.z + v.w * v.w;
#pragma unroll
    for (int off = 32; off; off >>= 1) ss += __shfl_xor(ss, off);

    unsigned short* ph = (isx ? xh : yh) + (size_t)r * DD + l * 4;
    *(ushort4*)ph = make_ushort4(f2bf(v.x), f2bf(v.y), f2bf(v.z), f2bf(v.w));
    if (l == 0) (isx ? nx : ny)[r] = sqrtf(ss);
}

// ---------------------------------------------------------------------------
// C[b,n,m] = 1 - <x_n,y_m>/max(|x_n||y_m|, 1e-8), single bf16 MFMA.
// Writes ONLY C (f32); E is recomputed in sink_fused from the same C values.
// 128x128 tile, BK=32, 256 thr. XOR-swizzled LDS. (Verbatim R11.)
// ---------------------------------------------------------------------------
__global__ __launch_bounds__(256) void gemm_cos_mfma(
        const unsigned short* __restrict__ xh, const unsigned short* __restrict__ yh,
        const float* __restrict__ nx, const float* __restrict__ ny,
        float* __restrict__ C) {
    int blk = blockIdx.x;
    int b = blk >> 4, ti = (blk >> 2) & 3, tj = blk & 3;
    __shared__ short Ah[128][32], Bh[128][32];
    const unsigned short* xbh = xh + ((size_t)b * NN + ti * 128) * DD;
    const unsigned short* ybh = yh + ((size_t)b * NN + tj * 128) * DD;
    int t = threadIdx.x, w = t >> 6, l = t & 63;
    int rw = w * 32, q = l >> 4, low = l & 15;

    f32x4 acc[2][8];
#pragma unroll
    for (int i = 0; i < 2; ++i)
#pragma unroll
        for (int j = 0; j < 8; ++j) acc[i][j] = (f32x4){0.f, 0.f, 0.f, 0.f};

    int sr = t >> 1, h = t & 1;               // staging: 2 threads/row
    int c0i = 2 * h, c1i = 2 * h + 1;         // logical 16B chunks
    int sw0 = (c0i ^ ((sr >> 1) & 3)) * 8;    // swizzled short offsets
    int sw1 = (c1i ^ ((sr >> 1) & 3)) * 8;

    for (int k0 = 0; k0 < DD; k0 += 32) {
        {
            const int4* ga = (const int4*)(xbh + (size_t)sr * DD + k0);
            const int4* gc = (const int4*)(ybh + (size_t)sr * DD + k0);
            int4 a0 = ga[c0i], a1 = ga[c1i];
            int4 c0 = gc[c0i], c1 = gc[c1i];
            *(int4*)&Ah[sr][sw0] = a0; *(int4*)&Ah[sr][sw1] = a1;
            *(int4*)&Bh[sr][sw0] = c0; *(int4*)&Bh[sr][sw1] = c1;
        }
        __syncthreads();

        bf16x8 ah[2];
#pragma unroll
        for (int ti2 = 0; ti2 < 2; ++ti2) {
            int m = rw + ti2 * 16 + low;
            int pq = (q ^ ((m >> 1) & 3)) * 8;
            ah[ti2] = *(const bf16x8*)&Ah[m][pq];
        }
#pragma unroll
        for (int tj2 = 0; tj2 < 8; ++tj2) {
            int n = tj2 * 16 + low;
            int pq = (q ^ ((n >> 1) & 3)) * 8;
            bf16x8 bh = *(const bf16x8*)&Bh[n][pq];
#pragma unroll
            for (int ti2 = 0; ti2 < 2; ++ti2)
                acc[ti2][tj2] = __builtin_amdgcn_mfma_f32_16x16x32_bf16(
                    ah[ti2], bh, acc[ti2][tj2], 0, 0, 0);
        }
        __syncthreads();
    }

    // epilogue: C/D layout col=lane&15, row=(lane>>4)*4+reg  [m89-corrected]
    float* Cb = C + (size_t)b * NN * NN;
#pragma unroll
    for (int ti2 = 0; ti2 < 2; ++ti2) {
#pragma unroll
        for (int tj2 = 0; tj2 < 8; ++tj2) {
            int gm0 = ti * 128 + rw + ti2 * 16 + q * 4;
            int gn  = tj * 128 + tj2 * 16 + low;
            float nyc = ny[b * NN + gn];
            f32x4 a = acc[ti2][tj2];
#pragma unroll
            for (int reg = 0; reg < 4; ++reg) {
                int gm = gm0 + reg;
                float d = 1.0f - a[reg] / fmaxf(nx[b * NN + gm] * nyc, F_NORMEPS);
                Cb[(size_t)gm * NN + gn] = d;
            }
        }
    }
}

// ---------------------------------------------------------------------------
// Fully fused Sinkhorn, R12 = R11 (proven 4-sync protocol, 256 blocks,
// 64-row stripes, E-from-C in registers) + two bit-identical micro-opts:
//  - steps 2+3 merged into ONE pass per row: each E element converted once
//    per iteration (was twice = 128 cvt/thread/iter); p[e] accumulates right
//    after A[i] finalizes (same i-ascending fmaf order -> identical fp ops),
//    and the serial shuffle chain of row i overlaps row i-1's p-updates.
//  - pi phase unroll 1 -> 2 (VGPR=60 has headroom; doubles loads in flight).
// ---------------------------------------------------------------------------
__global__ __launch_bounds__(512, 2) void sink_fused(
        const float* __restrict__ C,
        float* __restrict__ cp0, float* __restrict__ cp1,
        float* __restrict__ pi, float* __restrict__ cost,
        int* __restrict__ bars) {
    int blk = blockIdx.x;
    int xcd = blk & 7, qq = blk >> 3;
    int o = qq & 7;                       // stripe slot within batch
    int b = ((qq >> 3) << 3) | xcd;       // batch (8 stripes share blk%8/XCD)
    int tt = threadIdx.x, w = tt >> 6, l = tt & 63;
    int* flags = &bars[b * 64];           // 8 per-stripe flags, one line

    __shared__ float sW[NN];              // w_m (later reused for Q)
    __shared__ float sWP[8][NN];          // per-wave column partials
    __shared__ float sPart[8];

    // ---- E tile: compute fp16(exp(-10*C)) from f32 C, global -> registers,
    //      resident across all 15 iterations.
    int4 raw[8];
    {
        const float* Cl = C + ((size_t)b * NN + o * 64 + w * 8) * NN + 8 * l;
#pragma unroll
        for (int i = 0; i < 8; ++i) {
            float4 c0 = *(const float4*)(Cl + (size_t)i * NN);
            float4 c1 = *(const float4*)(Cl + (size_t)i * NN + 4);
            __half h[8];
            h[0] = __float2half(__expf(-INV_EPS * c0.x));
            h[1] = __float2half(__expf(-INV_EPS * c0.y));
            h[2] = __float2half(__expf(-INV_EPS * c0.z));
            h[3] = __float2half(__expf(-INV_EPS * c0.w));
            h[4] = __float2half(__expf(-INV_EPS * c1.x));
            h[5] = __float2half(__expf(-INV_EPS * c1.y));
            h[6] = __float2half(__expf(-INV_EPS * c1.z));
            h[7] = __float2half(__expf(-INV_EPS * c1.w));
            raw[i] = *(const int4*)h;
        }
    }

    float A[8], Pr[8];
#pragma unroll
    for (int i = 0; i < 8; ++i) { A[i] = 1.0f; Pr[i] = 0.0f; }
    float Br = 1.0f;                      // cumulative col scaling

    float* cpr = cp0;                     // read buffer
    float* cpw = cp1;                     // iter 1 writes cp1

    for (int t = 1; t <= 15; ++t) {
        // ---- step 1: finish v_{t-1}; t==1 has v_0=1, B_0=1
        if (t == 1) {
            sW[tt] = 1.0f;
        } else {
            // wait: all 8 stripes have completed iteration t-1
            if (tt < 8) {
                while (__hip_atomic_load(&flags[tt], __ATOMIC_RELAXED,
                                         __HIP_MEMORY_SCOPE_AGENT) < t - 1)
                    __builtin_amdgcn_s_sleep(1);
            }
            __syncthreads();
            float sv = 0.0f;
#pragma unroll
            for (int k = 0; k < 8; ++k)
                sv += __hip_atomic_load(
                    &cpr[(size_t)(b * 8 + k) * NN + tt],
                    __ATOMIC_RELAXED, __HIP_MEMORY_SCOPE_AGENT);
            float vv = MARG / (Br * sv + F_TINY);
            Br *= vv;                      // B_{t-1}
            sW[tt] = Br * vv;              // w_m
        }
        __syncthreads();                  // sW ready

        float wr[8];
        *(float4*)&wr[0] = *(const float4*)&sW[8 * l];
        *(float4*)&wr[4] = *(const float4*)&sW[8 * l + 4];

        // ---- steps 2+3 merged: one conversion pass per row; p[e]
        //      accumulates right after A[i] is finalized (same fp order
        //      as the split version -> bit-identical results).
        float p[8];
#pragma unroll
        for (int e = 0; e < 8; ++e) p[e] = 0.0f;
#pragma unroll
        for (int i = 0; i < 8; ++i) {
            const __half* hv = (const __half*)&raw[i];
            float f0 = __half2float(hv[0]), f1 = __half2float(hv[1]);
            float f2 = __half2float(hv[2]), f3 = __half2float(hv[3]);
            float f4 = __half2float(hv[4]), f5 = __half2float(hv[5]);
            float f6 = __half2float(hv[6]), f7 = __half2float(hv[7]);
            float s = 0.0f;
            s = fmaf(f0, wr[0], s); s = fmaf(f1, wr[1], s);
            s = fmaf(f2, wr[2], s); s = fmaf(f3, wr[3], s);
            s = fmaf(f4, wr[4], s); s = fmaf(f5, wr[5], s);
            s = fmaf(f6, wr[6], s); s = fmaf(f7, wr[7], s);
#pragma unroll
            for (int off = 32; off; off >>= 1) s += __shfl_xor(s, off);
            float uu = MARG / (A[i] * s + F_TINY);
            A[i] *= uu;
            if (t == 15) Pr[i] = A[i] * uu;   // P = A_15 * u_15 (all lanes)
            float ai = A[i];
            p[0] = fmaf(f0, ai, p[0]); p[1] = fmaf(f1, ai, p[1]);
            p[2] = fmaf(f2, ai, p[2]); p[3] = fmaf(f3, ai, p[3]);
            p[4] = fmaf(f4, ai, p[4]); p[5] = fmaf(f5, ai, p[5]);
            p[6] = fmaf(f6, ai, p[6]); p[7] = fmaf(f7, ai, p[7]);
        }
        *(float4*)&sWP[w][8 * l]     = make_float4(p[0], p[1], p[2], p[3]);
        *(float4*)&sWP[w][8 * l + 4] = make_float4(p[4], p[5], p[6], p[7]);
        __syncthreads();
        float cs = 0.0f;
#pragma unroll
        for (int ww = 0; ww < 8; ++ww) cs += sWP[ww][tt];
        cpw[(size_t)(b * 8 + o) * NN + tt] = cs;

        // ---- arrive: syncthreads drains vmcnt (cp stores at L2, L1 is
        //      write-through), then one flag STORE (no RMW chain).
        __syncthreads();
        if (tt == 0)
            __hip_atomic_store(&flags[o], t, __ATOMIC_RELAXED,
                               __HIP_MEMORY_SCOPE_AGENT);

        float* tmp = cpr; cpr = cpw; cpw = tmp;   // swap buffers
    }

    // ---- finish Q: wait for iter-15 flags, then full Q vector per block
    if (tt < 8) {
        while (__hip_atomic_load(&flags[tt], __ATOMIC_RELAXED,
                                 __HIP_MEMORY_SCOPE_AGENT) < 15)
            __builtin_amdgcn_s_sleep(1);
    }
    __syncthreads();
    {
        float sv = 0.0f;
#pragma unroll
        for (int k = 0; k < 8; ++k)
            sv += __hip_atomic_load(
                &cpr[(size_t)(b * 8 + k) * NN + tt],   // cp_15
                __ATOMIC_RELAXED, __HIP_MEMORY_SCOPE_AGENT);
        float vv = MARG / (Br * sv + F_TINY);           // Br = B_14
        sW[tt] = Br * vv * vv;            // Q_m = B_15 * v_15 (reuse sW)
    }
    __syncthreads();                      // Q visible block-wide

    // ---- pi phase: identical math to verified pi_cost (f32 C, __expf)
    float q0[8];
    *(float4*)&q0[0] = *(const float4*)&sW[4 * l];
    *(float4*)&q0[4] = *(const float4*)&sW[256 + 4 * l];
    const float* Cb = C + (size_t)b * NN * NN;
    float* pib = pi + (size_t)b * NN * NN;
    float csum = 0.0f;
#pragma unroll 2
    for (int i = 0; i < 8; ++i) {
        int r = o * 64 + w * 8 + i;
        float pf = Pr[i];
        const float* crow = Cb + (size_t)r * NN;
        float* prow = pib + (size_t)r * NN;
        float4 c0 = *(const float4*)(crow + 4 * l);
        float4 c1 = *(const float4*)(crow + 256 + 4 * l);
        float pv0 = pf * q0[0] * __expf(-INV_EPS * c0.x);
        float pv1 = pf * q0[1] * __expf(-INV_EPS * c0.y);
        float pv2 = pf * q0[2] * __expf(-INV_EPS * c0.z);
        float pv3 = pf * q0[3] * __expf(-INV_EPS * c0.w);
        float pv4 = pf * q0[4] * __expf(-INV_EPS * c1.x);
        float pv5 = pf * q0[5] * __expf(-INV_EPS * c1.y);
        float pv6 = pf * q0[6] * __expf(-INV_EPS * c1.z);
        float pv7 = pf * q0[7] * __expf(-INV_EPS * c1.w);
        *(float4*)(prow + 4 * l)       = make_float4(pv0, pv1, pv2, pv3);
        *(float4*)(prow + 256 + 4 * l) = make_float4(pv4, pv5, pv6, pv7);
        csum = fmaf(pv0, c0.x, csum); csum = fmaf(pv1, c0.y, csum);
        csum = fmaf(pv2, c0.z, csum); csum = fmaf(pv3, c0.w, csum);
        csum = fmaf(pv4, c1.x, csum); csum = fmaf(pv5, c1.y, csum);
        csum = fmaf(pv6, c1.z, csum); csum = fmaf(pv7, c1.w, csum);
    }
#pragma unroll
    for (int off = 32; off; off >>= 1) csum += __shfl_xor(csum, off);
    if (l == 0) sPart[w] = csum;
    __syncthreads();
    if (tt == 0) {
        float tot = 0.0f;
#pragma unroll
        for (int ww = 0; ww < 8; ++ww) tot += sPart[ww];
        atomicAdd(&cost[b], tot);
    }
}

// ---------------------------------------------------------------------------
extern "C" void kernel_launch(void* const* d_in, const int* in_sizes, int n_in,
                              void* d_out, int out_size, void* d_ws, size_t ws_size,
                              hipStream_t stream) {
    const float* x = (const float*)d_in[0];
    const float* y = (const float*)d_in[1];
    float* out  = (float*)d_out;
    float* cost = out;                                   // [32]
    float* pi   = out + 32;                              // [32*512*512]
    float* C    = out + 32 + (size_t)NB * NN * NN;       // [32*512*512]

    // Workspace: nx/ny, flags, bf16 inputs, cp double buffer.
    float* ws = (float*)d_ws;
    float* nx = ws;                                   // 16384 f
    float* ny = ws + 16384;                           // 16384 f
    int*  bars = (int*)(ws + 32768);                  // 2048 ints (flags)
    unsigned short* xh = (unsigned short*)(ws + 65536);       // 8.39 MB
    unsigned short* yh = xh + NELEM;                          // 8.39 MB
    float* cp0 = (float*)(yh + NELEM);                        // 0.52 MB
    float* cp1 = cp0 + (size_t)NB * 8 * NN;                   // 0.52 MB

    norms_convert<<<dim3(8192), dim3(256), 0, stream>>>(
        x, y, nx, ny, xh, yh, cost, bars);
    gemm_cos_mfma<<<dim3(512), dim3(256), 0, stream>>>(
        xh, yh, nx, ny, C);

    const float* C_p = C;
    float* cp0_p = cp0; float* cp1_p = cp1;
    float* pi_p = pi; float* cost_p = cost; int* bars_p = bars;
    void* args[] = { &C_p, &cp0_p, &cp1_p, &pi_p, &cost_p, &bars_p };
    hipLaunchCooperativeKernel(reinterpret_cast<void*>(sink_fused),
                               dim3(256), dim3(512), args, 0, stream);
}

// Round 13
// 177.398 us; speedup vs baseline: 5.5965x; 1.0393x over previous
//
#include <hip/hip_runtime.h>
#include <hip/hip_fp16.h>
#include <math.h>

#define NB 32
#define NN 512
#define DD 256

constexpr float INV_EPS   = 10.0f;
constexpr float F_TINY    = 1e-16f;
constexpr float F_NORMEPS = 1e-8f;
constexpr float MARG      = 1.0f / 512.0f;   // a = b = 1/n

// bars: one 256B line per batch; ints [b*64 + o] (o=0..7) hold the last
// completed iteration of stripe o of batch b (monotonic flags, no RMW).
#define BARS_N 2048

typedef __attribute__((ext_vector_type(8))) short bf16x8;
typedef __attribute__((ext_vector_type(4))) float f32x4;

__device__ __forceinline__ unsigned short f2bf(float f) {
    unsigned u = __float_as_uint(f);
    u += 0x7fffu + ((u >> 16) & 1u);          // round-to-nearest-even
    return (unsigned short)(u >> 16);
}
__device__ __forceinline__ int pack2(float a, float b) {
    return (int)f2bf(a) | ((int)f2bf(b) << 16);
}

// ---------------------------------------------------------------------------
// Fused norms + cosine GEMM:  C[b,n,m] = 1 - <x_n,y_m>/max(|x_n||y_m|,1e-8)
// Reads f32 x,y directly; staging converts f32->bf16 inline and accumulates
// row sum-of-squares across the k-loop (2 staging threads/row -> shfl_xor(1)
// partner reduce -> LDS norms for the epilogue). The separate norms_convert
// kernel and the 16.8 MB xh/yh round-trip are deleted. Writes ONLY C (f32);
// E is recomputed in sink_fused from the same C values.
// Staging k-ranges and XOR-swizzle indices map 1:1 onto the verified R5
// layout (chunk ci covers k-offsets k0+8*ci, 2 thr/row, h selects 16-float
// halves). Block 0 zeroes cost+bars. No spin loops — cannot hang.
// ---------------------------------------------------------------------------
__global__ __launch_bounds__(256) void gemm_cos_mfma(
        const float* __restrict__ x, const float* __restrict__ y,
        float* __restrict__ C, float* __restrict__ cost,
        int* __restrict__ bars) {
    int blk = blockIdx.x;
    int b = blk >> 4, ti = (blk >> 2) & 3, tj = blk & 3;
    if (blk == 0) {
        if (threadIdx.x < NB) cost[threadIdx.x] = 0.0f;
        for (int i = threadIdx.x; i < BARS_N; i += 256) bars[i] = 0;
    }
    __shared__ short Ah[128][32], Bh[128][32];
    __shared__ float sNx[128], sNy[128];
    const float* xb = x + ((size_t)b * NN + ti * 128) * DD;
    const float* yb = y + ((size_t)b * NN + tj * 128) * DD;
    int t = threadIdx.x, w = t >> 6, l = t & 63;
    int rw = w * 32, q = l >> 4, low = l & 15;

    f32x4 acc[2][8];
#pragma unroll
    for (int i = 0; i < 2; ++i)
#pragma unroll
        for (int j = 0; j < 8; ++j) acc[i][j] = (f32x4){0.f, 0.f, 0.f, 0.f};

    int sr = t >> 1, h = t & 1;               // staging: 2 threads/row
    int c0i = 2 * h, c1i = 2 * h + 1;         // logical 16B bf16 chunks
    int sw0 = (c0i ^ ((sr >> 1) & 3)) * 8;    // swizzled short offsets
    int sw1 = (c1i ^ ((sr >> 1) & 3)) * 8;
    float ssA = 0.0f, ssB = 0.0f;             // row sum-of-squares partials

    for (int k0 = 0; k0 < DD; k0 += 32) {
        {
            const float4* ga = (const float4*)(xb + (size_t)sr * DD + k0 + 16 * h);
            const float4* gc = (const float4*)(yb + (size_t)sr * DD + k0 + 16 * h);
            float4 a0 = ga[0], a1 = ga[1], a2 = ga[2], a3 = ga[3];
            float4 c0 = gc[0], c1 = gc[1], c2 = gc[2], c3 = gc[3];
            ssA += a0.x*a0.x + a0.y*a0.y + a0.z*a0.z + a0.w*a0.w;
            ssA += a1.x*a1.x + a1.y*a1.y + a1.z*a1.z + a1.w*a1.w;
            ssA += a2.x*a2.x + a2.y*a2.y + a2.z*a2.z + a2.w*a2.w;
            ssA += a3.x*a3.x + a3.y*a3.y + a3.z*a3.z + a3.w*a3.w;
            ssB += c0.x*c0.x + c0.y*c0.y + c0.z*c0.z + c0.w*c0.w;
            ssB += c1.x*c1.x + c1.y*c1.y + c1.z*c1.z + c1.w*c1.w;
            ssB += c2.x*c2.x + c2.y*c2.y + c2.z*c2.z + c2.w*c2.w;
            ssB += c3.x*c3.x + c3.y*c3.y + c3.z*c3.z + c3.w*c3.w;
            int4 pa0 = { pack2(a0.x,a0.y), pack2(a0.z,a0.w),
                         pack2(a1.x,a1.y), pack2(a1.z,a1.w) };
            int4 pa1 = { pack2(a2.x,a2.y), pack2(a2.z,a2.w),
                         pack2(a3.x,a3.y), pack2(a3.z,a3.w) };
            int4 pc0 = { pack2(c0.x,c0.y), pack2(c0.z,c0.w),
                         pack2(c1.x,c1.y), pack2(c1.z,c1.w) };
            int4 pc1 = { pack2(c2.x,c2.y), pack2(c2.z,c2.w),
                         pack2(c3.x,c3.y), pack2(c3.z,c3.w) };
            *(int4*)&Ah[sr][sw0] = pa0; *(int4*)&Ah[sr][sw1] = pa1;
            *(int4*)&Bh[sr][sw0] = pc0; *(int4*)&Bh[sr][sw1] = pc1;
        }
        __syncthreads();

        bf16x8 ah[2];
#pragma unroll
        for (int ti2 = 0; ti2 < 2; ++ti2) {
            int m = rw + ti2 * 16 + low;
            int pq = (q ^ ((m >> 1) & 3)) * 8;
            ah[ti2] = *(const bf16x8*)&Ah[m][pq];
        }
#pragma unroll
        for (int tj2 = 0; tj2 < 8; ++tj2) {
            int n = tj2 * 16 + low;
            int pq = (q ^ ((n >> 1) & 3)) * 8;
            bf16x8 bh = *(const bf16x8*)&Bh[n][pq];
#pragma unroll
            for (int ti2 = 0; ti2 < 2; ++ti2)
                acc[ti2][tj2] = __builtin_amdgcn_mfma_f32_16x16x32_bf16(
                    ah[ti2], bh, acc[ti2][tj2], 0, 0, 0);
        }
        __syncthreads();
    }

    // ---- finish row norms: partner thread (t^1) holds the other half
    float tA = ssA + __shfl_xor(ssA, 1);
    float tB = ssB + __shfl_xor(ssB, 1);
    if (h == 0) { sNx[sr] = sqrtf(tA); sNy[sr] = sqrtf(tB); }
    __syncthreads();

    // epilogue: C/D layout col=lane&15, row=(lane>>4)*4+reg  [m89-corrected]
    float* Cb = C + (size_t)b * NN * NN;
#pragma unroll
    for (int ti2 = 0; ti2 < 2; ++ti2) {
#pragma unroll
        for (int tj2 = 0; tj2 < 8; ++tj2) {
            int ml0 = rw + ti2 * 16 + q * 4;          // local m
            int nl  = tj2 * 16 + low;                 // local n
            int gm0 = ti * 128 + ml0;
            int gn  = tj * 128 + nl;
            float nyc = sNy[nl];
            f32x4 a = acc[ti2][tj2];
#pragma unroll
            for (int reg = 0; reg < 4; ++reg) {
                int gm = gm0 + reg;
                float d = 1.0f - a[reg] / fmaxf(sNx[ml0 + reg] * nyc, F_NORMEPS);
                Cb[(size_t)gm * NN + gn] = d;
            }
        }
    }
}

// ---------------------------------------------------------------------------
// Fully fused Sinkhorn — VERBATIM R12 (passing, 58.8 µs): proven 4-sync
// protocol, 256 blocks, 64-row stripes, E-from-C in registers, merged
// steps 2+3 (one conversion pass/row, bit-identical fp order), pi unroll 2.
// ---------------------------------------------------------------------------
__global__ __launch_bounds__(512, 2) void sink_fused(
        const float* __restrict__ C,
        float* __restrict__ cp0, float* __restrict__ cp1,
        float* __restrict__ pi, float* __restrict__ cost,
        int* __restrict__ bars) {
    int blk = blockIdx.x;
    int xcd = blk & 7, qq = blk >> 3;
    int o = qq & 7;                       // stripe slot within batch
    int b = ((qq >> 3) << 3) | xcd;       // batch (8 stripes share blk%8/XCD)
    int tt = threadIdx.x, w = tt >> 6, l = tt & 63;
    int* flags = &bars[b * 64];           // 8 per-stripe flags, one line

    __shared__ float sW[NN];              // w_m (later reused for Q)
    __shared__ float sWP[8][NN];          // per-wave column partials
    __shared__ float sPart[8];

    // ---- E tile: compute fp16(exp(-10*C)) from f32 C, global -> registers,
    //      resident across all 15 iterations.
    int4 raw[8];
    {
        const float* Cl = C + ((size_t)b * NN + o * 64 + w * 8) * NN + 8 * l;
#pragma unroll
        for (int i = 0; i < 8; ++i) {
            float4 c0 = *(const float4*)(Cl + (size_t)i * NN);
            float4 c1 = *(const float4*)(Cl + (size_t)i * NN + 4);
            __half h[8];
            h[0] = __float2half(__expf(-INV_EPS * c0.x));
            h[1] = __float2half(__expf(-INV_EPS * c0.y));
            h[2] = __float2half(__expf(-INV_EPS * c0.z));
            h[3] = __float2half(__expf(-INV_EPS * c0.w));
            h[4] = __float2half(__expf(-INV_EPS * c1.x));
            h[5] = __float2half(__expf(-INV_EPS * c1.y));
            h[6] = __float2half(__expf(-INV_EPS * c1.z));
            h[7] = __float2half(__expf(-INV_EPS * c1.w));
            raw[i] = *(const int4*)h;
        }
    }

    float A[8], Pr[8];
#pragma unroll
    for (int i = 0; i < 8; ++i) { A[i] = 1.0f; Pr[i] = 0.0f; }
    float Br = 1.0f;                      // cumulative col scaling

    float* cpr = cp0;                     // read buffer
    float* cpw = cp1;                     // iter 1 writes cp1

    for (int t = 1; t <= 15; ++t) {
        // ---- step 1: finish v_{t-1}; t==1 has v_0=1, B_0=1
        if (t == 1) {
            sW[tt] = 1.0f;
        } else {
            // wait: all 8 stripes have completed iteration t-1
            if (tt < 8) {
                while (__hip_atomic_load(&flags[tt], __ATOMIC_RELAXED,
                                         __HIP_MEMORY_SCOPE_AGENT) < t - 1)
                    __builtin_amdgcn_s_sleep(1);
            }
            __syncthreads();
            float sv = 0.0f;
#pragma unroll
            for (int k = 0; k < 8; ++k)
                sv += __hip_atomic_load(
                    &cpr[(size_t)(b * 8 + k) * NN + tt],
                    __ATOMIC_RELAXED, __HIP_MEMORY_SCOPE_AGENT);
            float vv = MARG / (Br * sv + F_TINY);
            Br *= vv;                      // B_{t-1}
            sW[tt] = Br * vv;              // w_m
        }
        __syncthreads();                  // sW ready

        float wr[8];
        *(float4*)&wr[0] = *(const float4*)&sW[8 * l];
        *(float4*)&wr[4] = *(const float4*)&sW[8 * l + 4];

        // ---- steps 2+3 merged: one conversion pass per row; p[e]
        //      accumulates right after A[i] is finalized (same fp order
        //      as the split version -> bit-identical results).
        float p[8];
#pragma unroll
        for (int e = 0; e < 8; ++e) p[e] = 0.0f;
#pragma unroll
        for (int i = 0; i < 8; ++i) {
            const __half* hv = (const __half*)&raw[i];
            float f0 = __half2float(hv[0]), f1 = __half2float(hv[1]);
            float f2 = __half2float(hv[2]), f3 = __half2float(hv[3]);
            float f4 = __half2float(hv[4]), f5 = __half2float(hv[5]);
            float f6 = __half2float(hv[6]), f7 = __half2float(hv[7]);
            float s = 0.0f;
            s = fmaf(f0, wr[0], s); s = fmaf(f1, wr[1], s);
            s = fmaf(f2, wr[2], s); s = fmaf(f3, wr[3], s);
            s = fmaf(f4, wr[4], s); s = fmaf(f5, wr[5], s);
            s = fmaf(f6, wr[6], s); s = fmaf(f7, wr[7], s);
#pragma unroll
            for (int off = 32; off; off >>= 1) s += __shfl_xor(s, off);
            float uu = MARG / (A[i] * s + F_TINY);
            A[i] *= uu;
            if (t == 15) Pr[i] = A[i] * uu;   // P = A_15 * u_15 (all lanes)
            float ai = A[i];
            p[0] = fmaf(f0, ai, p[0]); p[1] = fmaf(f1, ai, p[1]);
            p[2] = fmaf(f2, ai, p[2]); p[3] = fmaf(f3, ai, p[3]);
            p[4] = fmaf(f4, ai, p[4]); p[5] = fmaf(f5, ai, p[5]);
            p[6] = fmaf(f6, ai, p[6]); p[7] = fmaf(f7, ai, p[7]);
        }
        *(float4*)&sWP[w][8 * l]     = make_float4(p[0], p[1], p[2], p[3]);
        *(float4*)&sWP[w][8 * l + 4] = make_float4(p[4], p[5], p[6], p[7]);
        __syncthreads();
        float cs = 0.0f;
#pragma unroll
        for (int ww = 0; ww < 8; ++ww) cs += sWP[ww][tt];
        cpw[(size_t)(b * 8 + o) * NN + tt] = cs;

        // ---- arrive: syncthreads drains vmcnt (cp stores at L2, L1 is
        //      write-through), then one flag STORE (no RMW chain).
        __syncthreads();
        if (tt == 0)
            __hip_atomic_store(&flags[o], t, __ATOMIC_RELAXED,
                               __HIP_MEMORY_SCOPE_AGENT);

        float* tmp = cpr; cpr = cpw; cpw = tmp;   // swap buffers
    }

    // ---- finish Q: wait for iter-15 flags, then full Q vector per block
    if (tt < 8) {
        while (__hip_atomic_load(&flags[tt], __ATOMIC_RELAXED,
                                 __HIP_MEMORY_SCOPE_AGENT) < 15)
            __builtin_amdgcn_s_sleep(1);
    }
    __syncthreads();
    {
        float sv = 0.0f;
#pragma unroll
        for (int k = 0; k < 8; ++k)
            sv += __hip_atomic_load(
                &cpr[(size_t)(b * 8 + k) * NN + tt],   // cp_15
                __ATOMIC_RELAXED, __HIP_MEMORY_SCOPE_AGENT);
        float vv = MARG / (Br * sv + F_TINY);           // Br = B_14
        sW[tt] = Br * vv * vv;            // Q_m = B_15 * v_15 (reuse sW)
    }
    __syncthreads();                      // Q visible block-wide

    // ---- pi phase: identical math to verified pi_cost (f32 C, __expf)
    float q0[8];
    *(float4*)&q0[0] = *(const float4*)&sW[4 * l];
    *(float4*)&q0[4] = *(const float4*)&sW[256 + 4 * l];
    const float* Cb = C + (size_t)b * NN * NN;
    float* pib = pi + (size_t)b * NN * NN;
    float csum = 0.0f;
#pragma unroll 2
    for (int i = 0; i < 8; ++i) {
        int r = o * 64 + w * 8 + i;
        float pf = Pr[i];
        const float* crow = Cb + (size_t)r * NN;
        float* prow = pib + (size_t)r * NN;
        float4 c0 = *(const float4*)(crow + 4 * l);
        float4 c1 = *(const float4*)(crow + 256 + 4 * l);
        float pv0 = pf * q0[0] * __expf(-INV_EPS * c0.x);
        float pv1 = pf * q0[1] * __expf(-INV_EPS * c0.y);
        float pv2 = pf * q0[2] * __expf(-INV_EPS * c0.z);
        float pv3 = pf * q0[3] * __expf(-INV_EPS * c0.w);
        float pv4 = pf * q0[4] * __expf(-INV_EPS * c1.x);
        float pv5 = pf * q0[5] * __expf(-INV_EPS * c1.y);
        float pv6 = pf * q0[6] * __expf(-INV_EPS * c1.z);
        float pv7 = pf * q0[7] * __expf(-INV_EPS * c1.w);
        *(float4*)(prow + 4 * l)       = make_float4(pv0, pv1, pv2, pv3);
        *(float4*)(prow + 256 + 4 * l) = make_float4(pv4, pv5, pv6, pv7);
        csum = fmaf(pv0, c0.x, csum); csum = fmaf(pv1, c0.y, csum);
        csum = fmaf(pv2, c0.z, csum); csum = fmaf(pv3, c0.w, csum);
        csum = fmaf(pv4, c1.x, csum); csum = fmaf(pv5, c1.y, csum);
        csum = fmaf(pv6, c1.z, csum); csum = fmaf(pv7, c1.w, csum);
    }
#pragma unroll
    for (int off = 32; off; off >>= 1) csum += __shfl_xor(csum, off);
    if (l == 0) sPart[w] = csum;
    __syncthreads();
    if (tt == 0) {
        float tot = 0.0f;
#pragma unroll
        for (int ww = 0; ww < 8; ++ww) tot += sPart[ww];
        atomicAdd(&cost[b], tot);
    }
}

// ---------------------------------------------------------------------------
extern "C" void kernel_launch(void* const* d_in, const int* in_sizes, int n_in,
                              void* d_out, int out_size, void* d_ws, size_t ws_size,
                              hipStream_t stream) {
    const float* x = (const float*)d_in[0];
    const float* y = (const float*)d_in[1];
    float* out  = (float*)d_out;
    float* cost = out;                                   // [32]
    float* pi   = out + 32;                              // [32*512*512]
    float* C    = out + 32 + (size_t)NB * NN * NN;       // [32*512*512]

    // Workspace: flags + cp double buffer only (xh/yh/Ef all deleted).
    int* bars = (int*)d_ws;                                   // 8 KB
    float* cp0 = (float*)((char*)d_ws + 8192);                // 0.52 MB
    float* cp1 = cp0 + (size_t)NB * 8 * NN;                   // 0.52 MB

    gemm_cos_mfma<<<dim3(512), dim3(256), 0, stream>>>(
        x, y, C, cost, bars);

    const float* C_p = C;
    float* cp0_p = cp0; float* cp1_p = cp1;
    float* pi_p = pi; float* cost_p = cost; int* bars_p = bars;
    void* args[] = { &C_p, &cp0_p, &cp1_p, &pi_p, &cost_p, &bars_p };
    hipLaunchCooperativeKernel(reinterpret_cast<void*>(sink_fused),
                               dim3(256), dim3(512), args, 0, stream);
}